// Round 7
// baseline (1200.812 us; speedup 1.0000x reference)
//
#include <hip/hip_runtime.h>
#include <math.h>

#define N_ROWS 65536
#define CB 1024
#define SPLITS 4
#define JS (CB / SPLITS)     // 256 codebook entries per split
#define NFILLER 256          // zero-filler blocks (bids 0..255)
#define SLICE_F 196608       // floats per 64-row slice of out3 (64*3*1024)

typedef float v4f __attribute__((ext_vector_type(4)));

// ---------------------------------------------------------------------------
// Exact emulation of numpy's pairwise_sum for n=64 fp32 (AVX-512 path).
// fp contract OFF so the squares are not fused into the adds.
// ---------------------------------------------------------------------------
__device__ __forceinline__ float tree_sum64_sq(const float* x) {
#pragma clang fp contract(off)
    float sq[64];
#pragma unroll
    for (int i = 0; i < 64; ++i) sq[i] = x[i] * x[i];
    float s[16];
#pragma unroll
    for (int l = 0; l < 16; ++l) s[l] = (sq[l] + sq[l + 16]) + (sq[l + 32] + sq[l + 48]);
    float t[8];
#pragma unroll
    for (int l = 0; l < 8; ++l) t[l] = s[l] + s[l + 8];
    float u[4];
#pragma unroll
    for (int l = 0; l < 4; ++l) u[l] = t[l] + t[l + 4];
    float v0 = u[0] + u[2];
    float v1 = u[1] + u[3];
    return v0 + v1;
}

// sorted-triple insert, strict < (ties keep earlier-inserted = lower index,
// matching jax.lax.top_k stable tie-breaking when fed in ascending index order)
__device__ __forceinline__ void top3_insert(float d, int j,
                                            float& v0, float& v1, float& v2,
                                            int& i0, int& i1, int& i2) {
    bool b0 = d < v0, b1 = d < v1, b2 = d < v2;
    v2 = b1 ? v1 : (b2 ? d : v2);
    i2 = b1 ? i1 : (b2 ? j : i2);
    v1 = b0 ? v0 : (b1 ? d : v1);
    i1 = b0 ? i0 : (b1 ? j : i1);
    v0 = b0 ? d : v0;
    i0 = b0 ? j : i0;
}

// ---------------------------------------------------------------------------
// B[j] = np.sum(emb[j]**2) (exact tree emulation) + zero hist/lossAcc/flags.
// flags[1024]: one per 64-row slice of out3. 0=unfilled, 3=filler writing,
// 1=zeros durable, 2=claimed by scorer fallback.
// ---------------------------------------------------------------------------
__global__ __launch_bounds__(256) void prep_kernel(const float* __restrict__ emb,
                                                   float* __restrict__ B,
                                                   int* __restrict__ hist,
                                                   float* __restrict__ lossAcc,
                                                   int* __restrict__ flags) {
    int j = blockIdx.x * 256 + threadIdx.x;
    if (j >= CB) return;
    float e[64];
    const float4* e4 = (const float4*)(emb + (size_t)j * 64);
#pragma unroll
    for (int k = 0; k < 16; ++k) {
        float4 v = e4[k];
        e[4 * k] = v.x; e[4 * k + 1] = v.y; e[4 * k + 2] = v.z; e[4 * k + 3] = v.w;
    }
    B[j] = tree_sum64_sq(e);
    hist[j] = 0;
    flags[j] = 0;
    if (j == 0) *lossAcc = 0.0f;
}

// ---------------------------------------------------------------------------
// Single dispatch, two roles (R4 lesson: stores must NOT share a wave with
// the latency-critical scoring loop — in-order issue makes a vmcnt-full
// store block the next s_load, serializing the phases).
//
//  bids [0,256):    FILLER blocks — stream the 805 MB of out3 zeros (the
//                   fastest write pattern measured on this chip, ~2.6 TB/s)
//                   starting at t=0, concurrent with all scoring.
//                   Per slice: CAS(0->3) claim, zero, fence, release flag=1.
//  bids [256,1280): SCORER blocks — unchanged bit-exact score/merge/epilogue;
//                   then acquire-spin on the slice flag and scatter <=192
//                   "one" positions. Bounded spin -> CAS(0->2) self-fill
//                   fallback (correct under any scheduler; no deadlock).
//
// __launch_bounds__(256,5): 5 blocks/CU -> all 1280 blocks co-resident
// (per CU: 1 filler + 4 scorers, scorer occupancy unchanged vs R3).
// Cross-XCD visibility: filler __threadfence + agent release store; scorer
// agent acquire load + threadfence before the ones (per-XCD L2s non-coherent).
// ---------------------------------------------------------------------------
__global__ __launch_bounds__(256, 5) void main_kernel(const float* __restrict__ z,
                                                      const float* __restrict__ emb,
                                                      const float* __restrict__ B,
                                                      float* __restrict__ out0,
                                                      float* __restrict__ out3f,
                                                      float* __restrict__ out4,
                                                      int* __restrict__ hist,
                                                      float* __restrict__ lossAcc,
                                                      int* __restrict__ flags) {
    int bid = blockIdx.x;
    int t = threadIdx.x;

    if (bid < NFILLER) {
        // ---------------- filler role ----------------
        __shared__ int fown[4];
        if (t == 0) {
#pragma unroll
            for (int q = 0; q < 4; ++q)
                fown[q] = (atomicCAS(&flags[bid * 4 + q], 0, 3) == 0) ? 1 : 0;
        }
        __syncthreads();
        v4f zz = {0.0f, 0.0f, 0.0f, 0.0f};
        for (int q = 0; q < 4; ++q) {
            if (!fown[q]) continue;
            float* Sb = out3f + (size_t)(bid * 4 + q) * SLICE_F;  // == 8 mod 16 B
            v4f* S4 = (v4f*)(Sb + 2);                             // aligned body
            for (int m = t; m < 49151; m += 256) S4[m] = zz;
            if (t == 0) {
                Sb[0] = 0.0f; Sb[1] = 0.0f;
                Sb[SLICE_F - 2] = 0.0f; Sb[SLICE_F - 1] = 0.0f;
            }
        }
        __syncthreads();              // every wave drains vmcnt before s_barrier
        if (t == 0) {
            __threadfence();          // agent-scope release of the zero stream
#pragma unroll
            for (int q = 0; q < 4; ++q)
                if (fown[q])
                    __hip_atomic_store(&flags[bid * 4 + q], 1,
                                       __ATOMIC_RELEASE, __HIP_MEMORY_SCOPE_AGENT);
        }
        return;
    }

    // ---------------- scorer role (bit-identical math to R3..R6) ----------------
    __shared__ float sD[SPLITS][64][3];
    __shared__ int   sI[SPLITS][64][3];

    int g = bid - NFILLER;                                // row-group / slice id
    int r = t & 63;
    int split = __builtin_amdgcn_readfirstlane(t >> 6);   // uniform -> scalar loads
    int row = g * 64 + r;

    float zr[64];
    const float4* z4 = (const float4*)(z + (size_t)row * 64);
#pragma unroll
    for (int k = 0; k < 16; ++k) {
        float4 v = z4[k];
        zr[4 * k] = v.x; zr[4 * k + 1] = v.y; zr[4 * k + 2] = v.z; zr[4 * k + 3] = v.w;
    }
    float A = tree_sum64_sq(zr);

    float v0 = 3.402823466e38f, v1 = 3.402823466e38f, v2 = 3.402823466e38f;
    int i0 = 0, i1 = 0, i2 = 0;
    int jbase = split * JS;

#pragma unroll 2
    for (int jj = 0; jj < JS; ++jj) {
        int j = jbase + jj;                   // uniform (split is readfirstlane'd)
        const float4* e4 = (const float4*)(emb + (size_t)j * 64);
        float Bj = B[j];                      // uniform -> scalar load
        float acc = 0.0f;
#pragma unroll
        for (int k = 0; k < 16; ++k) {
            float4 e = e4[k];                 // uniform -> scalar loads
            acc = fmaf(zr[4 * k],     e.x, acc);
            acc = fmaf(zr[4 * k + 1], e.y, acc);
            acc = fmaf(zr[4 * k + 2], e.z, acc);
            acc = fmaf(zr[4 * k + 3], e.w, acc);
        }
        float d = (A + Bj) - 2.0f * acc;      // fma-contraction bit-identical
        top3_insert(d, j, v0, v1, v2, i0, i1, i2);
    }

    sD[split][r][0] = v0; sD[split][r][1] = v1; sD[split][r][2] = v2;
    sI[split][r][0] = i0; sI[split][r][1] = i1; sI[split][r][2] = i2;
    __syncthreads();

    if (t < 64) {                             // wave 0: zr holds row's z (split 0)
        float m0 = 3.402823466e38f, m1 = 3.402823466e38f, m2 = 3.402823466e38f;
        int j0 = 0, j1 = 0, j2 = 0;
#pragma unroll
        for (int s = 0; s < SPLITS; ++s) {    // ascending split = ascending index
#pragma unroll
            for (int u = 0; u < 3; ++u)
                top3_insert(sD[s][r][u], sI[s][r][u], m0, m1, m2, j0, j1, j2);
        }

        // ---- epilogue first (overlaps the flag wait) ----
        const float4* e0q = (const float4*)(emb + (size_t)j0 * 64);
        const float4* e1q = (const float4*)(emb + (size_t)j1 * 64);
        const float4* e2q = (const float4*)(emb + (size_t)j2 * 64);
        v4f* o4 = (v4f*)(out0 + (size_t)row * 64);

        float lsum = 0.0f;
#pragma unroll
        for (int k4 = 0; k4 < 16; ++k4) {
            float4 a = e0q[k4], b = e1q[k4], c = e2q[k4];   // vectorized gathers
            float zx = zr[4 * k4], zy = zr[4 * k4 + 1];
            float zz2 = zr[4 * k4 + 2], zw = zr[4 * k4 + 3];
            v4f st;
            float zq, df;
            zq = ((a.x + b.x) + c.x) / 3.0f; df = zq - zx;  st.x = zx  + df; lsum = fmaf(df, df, lsum);
            zq = ((a.y + b.y) + c.y) / 3.0f; df = zq - zy;  st.y = zy  + df; lsum = fmaf(df, df, lsum);
            zq = ((a.z + b.z) + c.z) / 3.0f; df = zq - zz2; st.z = zz2 + df; lsum = fmaf(df, df, lsum);
            zq = ((a.w + b.w) + c.w) / 3.0f; df = zq - zw;  st.w = zw  + df; lsum = fmaf(df, df, lsum);
            o4[k4] = st;                                    // plain store
        }

        size_t ob = (size_t)row * 3;
        out4[ob]     = (float)j0;
        out4[ob + 1] = (float)j1;
        out4[ob + 2] = (float)j2;
        atomicAdd(&hist[j0], 1);
        atomicAdd(&hist[j1], 1);
        atomicAdd(&hist[j2], 1);

#pragma unroll
        for (int off = 32; off >= 1; off >>= 1) lsum += __shfl_down(lsum, off);
        if (r == 0) atomicAdd(lossAcc, lsum);

        // ---- wait for this slice's zeros, then scatter the ones ----
        int selfown = 0;
        if (r == 0) {
            int it = 0;
            while (1) {
                int v = __hip_atomic_load(&flags[g], __ATOMIC_ACQUIRE,
                                          __HIP_MEMORY_SCOPE_AGENT);
                if (v == 1) break;
                if (v == 0 && ++it > 1500) {         // ~0.75 ms: filler never ran
                    int old = atomicCAS(&flags[g], 0, 2);
                    if (old == 0) { selfown = 1; break; }
                    if (old == 1) break;
                    it = 0;                          // filler mid-write: keep waiting
                }
                __builtin_amdgcn_s_sleep(10);
            }
        }
        selfown = __shfl(selfown, 0);
        __threadfence();                             // acquire on all exit paths

        if (selfown) {
            // fallback: wave 0 writes its own slice, ones inline (R3 pattern)
            float* P = out3f + (size_t)g * SLICE_F + (size_t)r * 3072; // ==8 mod 16B
            int o0 = j0, o1 = 1024 + j1, o2 = 2048 + j2;
            P[0] = (o0 == 0) ? 1.0f : 0.0f;
            P[1] = (o0 == 1) ? 1.0f : 0.0f;
            v4f* P4 = (v4f*)(P + 2);
            for (int m = 0; m < 767; ++m) {
                int e = 2 + 4 * m;
                v4f w;
                w.x = (e     == o0 || e     == o1 || e     == o2) ? 1.0f : 0.0f;
                w.y = (e + 1 == o0 || e + 1 == o1 || e + 1 == o2) ? 1.0f : 0.0f;
                w.z = (e + 2 == o0 || e + 2 == o1 || e + 2 == o2) ? 1.0f : 0.0f;
                w.w = (e + 3 == o0 || e + 3 == o1 || e + 3 == o2) ? 1.0f : 0.0f;
                P4[m] = w;
            }
            P[3070] = (3070 == o2) ? 1.0f : 0.0f;    // o0,o1 < 3070 always
            P[3071] = (3071 == o2) ? 1.0f : 0.0f;
        } else {
            size_t sb = (size_t)row * 3072;
            out3f[sb + j0]        = 1.0f;
            out3f[sb + 1024 + j1] = 1.0f;
            out3f[sb + 2048 + j2] = 1.0f;
        }
    }
}

// ---------------------------------------------------------------------------
// Perplexity from histogram + loss finalize (unchanged).
// ---------------------------------------------------------------------------
__global__ __launch_bounds__(256) void finalize_kernel(const int* __restrict__ hist,
                                                       const float* __restrict__ lossAcc,
                                                       float* __restrict__ out1,
                                                       float* __restrict__ out2) {
    __shared__ float red[256];
    int t = threadIdx.x;
    float local = 0.0f;
    for (int b = t; b < CB; b += 256) {
        float em = (float)hist[b] / 196608.0f;
        local += em * logf(em + 1e-10f);
    }
    red[t] = local;
    __syncthreads();
    for (int s = 128; s >= 1; s >>= 1) {
        if (t < s) red[t] += red[t + s];
        __syncthreads();
    }
    if (t == 0) {
        *out2 = expf(-red[0]);
        float m = *lossAcc / 4194304.0f;
        *out1 = 0.25f * m + m;     // BETA_C*mse + mse
    }
}

extern "C" void kernel_launch(void* const* d_in, const int* in_sizes, int n_in,
                              void* d_out, int out_size, void* d_ws, size_t ws_size,
                              hipStream_t stream) {
    const float* z   = (const float*)d_in[0];   // [16,64,64,64] -> 65536 x 64
    const float* emb = (const float*)d_in[1];   // [1024, 64]

    float* out  = (float*)d_out;
    float* out0 = out;                                    // z_q_st  4194304
    float* out1 = out + 4194304;                          // loss    1
    float* out2 = out + 4194305;                          // perplexity 1
    float* out3 = out + 4194306;                          // encodings 201326592
    float* out4 = out + 4194306 + 201326592ll;            // topk_idx (as float) 196608

    int*   hist    = (int*)d_ws;                          // 1024 ints @ 0
    float* lossAcc = (float*)((char*)d_ws + 4096);        // 1 float
    float* B       = (float*)((char*)d_ws + 8192);        // 1024 floats
    int*   flags   = (int*)((char*)d_ws + 12288);         // 1024 ints (slice flags)

    prep_kernel<<<4, 256, 0, stream>>>(emb, B, hist, lossAcc, flags);
    main_kernel<<<NFILLER + N_ROWS / 64, 256, 0, stream>>>(z, emb, B, out0, out3,
                                                           out4, hist, lossAcc, flags);
    finalize_kernel<<<1, 256, 0, stream>>>(hist, lossAcc, out1, out2);
}